// Round 1
// baseline (665.149 us; speedup 1.0000x reference)
//
#include <hip/hip_runtime.h>
#include <hip/hip_bf16.h>
#include <stdint.h>
#include <math.h>

#define DIM   1024
#define SEQ   2048
#define BATCH 8
#define BSD   (BATCH * SEQ * DIM)      // 16777216
#define DD    (DIM * DIM)              // 1048576

typedef __attribute__((ext_vector_type(8))) short short8;
typedef __attribute__((ext_vector_type(4))) float floatx4;
typedef unsigned int u32;
typedef unsigned short ushort_t;

#define GLOAD_LDS16(gptr, lptr)                                                   \
    __builtin_amdgcn_global_load_lds(                                             \
        (const __attribute__((address_space(1))) u32*)(gptr),                     \
        (__attribute__((address_space(3))) u32*)(lptr), 16, 0, 0)

__device__ __forceinline__ uint2 pack4bf(float a, float b, float c, float d) {
    union { __hip_bfloat162 h; unsigned u; } p0, p1;
    p0.h = __float22bfloat162_rn(float2{a, b});
    p1.h = __float22bfloat162_rn(float2{c, d});
    return uint2{p0.u, p1.u};
}

// ---------------- fp32 -> bf16 convert (ctx folded into q/k inputs) -----------
__global__ __launch_bounds__(256) void convert_kernel(
    const float* __restrict__ q, const float* __restrict__ k, const float* __restrict__ v,
    const float* __restrict__ ctx,
    const float* __restrict__ Wq, const float* __restrict__ Wk, const float* __restrict__ Wv,
    ushort_t* __restrict__ xq, ushort_t* __restrict__ xk, ushort_t* __restrict__ xv,
    ushort_t* __restrict__ wq, ushort_t* __restrict__ wk, ushort_t* __restrict__ wv)
{
    const long idx = (long)blockIdx.x * 256 + threadIdx.x;
    const long T  = BSD / 4;   // 2^22 float4 groups per tensor
    const long W4 = DD / 4;    // 2^18
    if (idx < 3 * T) {
        const int  seg = (int)(idx >> 22);
        const long off = idx & (T - 1);
        const float* src = (seg == 0) ? q : (seg == 1) ? k : v;
        ushort_t*    dst = (seg == 0) ? xq : (seg == 1) ? xk : xv;
        float4 x = ((const float4*)src)[off];
        if (seg < 2) {
            const float4 c = ((const float4*)ctx)[off & (DIM / 4 - 1)];
            x.x += c.x; x.y += c.y; x.z += c.z; x.w += c.w;
        }
        ((uint2*)dst)[off] = pack4bf(x.x, x.y, x.z, x.w);
    } else {
        const long r   = idx - 3 * T;
        const int  seg = (int)(r >> 18);
        const long off = r & (W4 - 1);
        const float* src = (seg == 0) ? Wq : (seg == 1) ? Wk : Wv;
        ushort_t*    dst = (seg == 0) ? wq : (seg == 1) ? wk : wv;
        const float4 x = ((const float4*)src)[off];
        ((uint2*)dst)[off] = pack4bf(x.x, x.y, x.z, x.w);
    }
}

// ---------------- bf16 NT GEMM, m97-style (global_load_lds w=16) --------------
// out[m,n] = sum_d X[m,d]*W[n,d] + bias[n].
// transpose_out=0: out [B*S, D] bf16 row-major; =1: out [B, D, S] bf16 (vT).
__global__ __launch_bounds__(256) void gemm_bf16(
    const ushort_t* __restrict__ X, const ushort_t* __restrict__ W,
    const float* __restrict__ bias, ushort_t* __restrict__ out, int transpose_out)
{
    __shared__ ushort_t As[128 * 64];   // linear, no pad (global_load_lds constraint)
    __shared__ ushort_t Bs[128 * 64];

    const int tid  = threadIdx.x;
    const int lane = tid & 63;
    const int wave = tid >> 6;
    const int quad = lane >> 4;
    const int l16  = lane & 15;
    const int wy = wave >> 1, wx = wave & 1;
    const int row0 = blockIdx.x * 128;
    const int col0 = blockIdx.y * 128;

    floatx4 acc[4][4];
#pragma unroll
    for (int i = 0; i < 4; ++i)
#pragma unroll
        for (int j = 0; j < 4; ++j)
            acc[i][j] = (floatx4){0.f, 0.f, 0.f, 0.f};

    const int srow = lane >> 3;         // 0..7 within slot
    const int scol = (lane & 7) * 8;    // ushort offset, 16B granules

    for (int k0 = 0; k0 < DIM; k0 += 64) {
#pragma unroll
        for (int i = 0; i < 4; ++i) {
            const int slot = wave * 4 + i;          // 0..15, 8 rows each
            const int grow = slot * 8 + srow;
            GLOAD_LDS16(&X[(size_t)(row0 + grow) * DIM + k0 + scol],
                        &As[slot * 512 + lane * 8]);
            GLOAD_LDS16(&W[(size_t)(col0 + grow) * DIM + k0 + scol],
                        &Bs[slot * 512 + lane * 8]);
        }
        __syncthreads();

        short8 af[4][2], bfr[4][2];
#pragma unroll
        for (int t = 0; t < 4; ++t)
#pragma unroll
            for (int ks = 0; ks < 2; ++ks) {
                af[t][ks]  = *(const short8*)&As[(wy * 64 + t * 16 + l16) * 64 + ks * 32 + quad * 8];
                bfr[t][ks] = *(const short8*)&Bs[(wx * 64 + t * 16 + l16) * 64 + ks * 32 + quad * 8];
            }
#pragma unroll
        for (int ks = 0; ks < 2; ++ks)
#pragma unroll
            for (int mt = 0; mt < 4; ++mt)
#pragma unroll
                for (int nt = 0; nt < 4; ++nt)
                    acc[mt][nt] = __builtin_amdgcn_mfma_f32_16x16x32_bf16(
                        af[mt][ks], bfr[nt][ks], acc[mt][nt], 0, 0, 0);
        __syncthreads();
    }

    // epilogue: +bias, bf16 store. C/D: col=l16, row=quad*4+reg.
#pragma unroll
    for (int nt = 0; nt < 4; ++nt) {
        const int n = col0 + wx * 64 + nt * 16 + l16;
        const float bz = bias[n];
#pragma unroll
        for (int mt = 0; mt < 4; ++mt) {
            const int mbase = row0 + wy * 64 + mt * 16 + quad * 4;
            const floatx4 a = acc[mt][nt];
            if (!transpose_out) {
#pragma unroll
                for (int rg = 0; rg < 4; ++rg) {
                    union { __hip_bfloat16 h; ushort_t u; } cv;
                    cv.h = __float2bfloat16(a[rg] + bz);
                    out[(size_t)(mbase + rg) * DIM + n] = cv.u;
                }
            } else {
                const int bb = mbase >> 11;          // /SEQ
                const int ss = mbase & (SEQ - 1);
                *(uint2*)&out[((size_t)bb * DIM + n) * SEQ + ss] =
                    pack4bf(a[0] + bz, a[1] + bz, a[2] + bz, a[3] + bz);
            }
        }
    }
}

// ---------------- flash attention, causal, Br=32, Bc=32, 8 waves --------------
// Load-balanced: each block runs TWO q-tiles (t, 63-t) sequentially; iteration
// count (t+1) + (64-t) = 65 for every block -> zero tail imbalance.
// Wave w: QK^T over D-chunk [w*128, w*128+128); PV over out-cols same chunk.
// Partials reduced via LDS. 1 block/CU.
__global__ __launch_bounds__(512, 2) void attn_kernel(
    const ushort_t* __restrict__ Q, const ushort_t* __restrict__ K,
    const ushort_t* __restrict__ VT, float* __restrict__ out)
{
    __shared__ float Sp[8 * 32 * 40];        // [wave][row 32][col 32 pad 40] fp32, 40KB
    __shared__ ushort_t Pl[32 * 40];         // P bf16, A-frag layout
    __shared__ float mS[32], lS[32], aS[32];

    const int tid  = threadIdx.x;
    const int lane = tid & 63;
    const int wave = tid >> 6;               // 0..7 = D-chunk
    const int quad = lane >> 4;
    const int l16  = lane & 15;

    const int by = blockIdx.x & 7;           // batch <-> XCD affinity
    const int p  = blockIdx.x >> 3;          // pair index 0..31

    const size_t qrow = (size_t)by * SEQ;
    const size_t vrow = (size_t)by * DIM;
    const int dchunk = wave * 128;

    const int rr = tid >> 4;                 // softmax row 0..31 (16 threads/row)
    const int c0 = (tid & 15) << 1;          // col pair

    for (int pass = 0; pass < 2; ++pass) {
        const int t    = pass ? (63 - p) : p;    // q-tile (32 rows)
        const int q0   = t * 32;
        const int jmax = t;                      // Bc=32 k-tiles: 0..t

        if (tid < 32) { mS[tid] = -INFINITY; lS[tid] = 0.f; aS[tid] = 0.f; }

        // resident Q fragments: 32 rows x 128 cols for this wave  (32 VGPRs)
        short8 qa[2][4];
#pragma unroll
        for (int mt = 0; mt < 2; ++mt)
#pragma unroll
            for (int ks = 0; ks < 4; ++ks)
                qa[mt][ks] = *(const short8*)
                    &Q[(qrow + q0 + mt * 16 + l16) * DIM + dchunk + ks * 32 + quad * 8];

        floatx4 o[2][8];                     // 32 rows x 128 cols  (64 VGPRs)
#pragma unroll
        for (int mt = 0; mt < 2; ++mt)
#pragma unroll
            for (int nt = 0; nt < 8; ++nt)
                o[mt][nt] = (floatx4){0.f, 0.f, 0.f, 0.f};

        __syncthreads();                     // mS/lS/aS init visible

        for (int j = 0; j <= jmax; ++j) {
            // ---- K fragments for this wave's D-chunk (transient) ----
            short8 kb[2][4];
#pragma unroll
            for (int nt = 0; nt < 2; ++nt)
#pragma unroll
                for (int ks = 0; ks < 4; ++ks)
                    kb[nt][ks] = *(const short8*)
                        &K[(qrow + j * 32 + nt * 16 + l16) * DIM + dchunk + ks * 32 + quad * 8];

            // ---- QK^T partial ----
#pragma unroll
            for (int mt = 0; mt < 2; ++mt) {
                floatx4 s0 = (floatx4){0.f, 0.f, 0.f, 0.f};
                floatx4 s1 = (floatx4){0.f, 0.f, 0.f, 0.f};
#pragma unroll
                for (int ks = 0; ks < 4; ++ks) {
                    s0 = __builtin_amdgcn_mfma_f32_16x16x32_bf16(qa[mt][ks], kb[0][ks], s0, 0, 0, 0);
                    s1 = __builtin_amdgcn_mfma_f32_16x16x32_bf16(qa[mt][ks], kb[1][ks], s1, 0, 0, 0);
                }
#pragma unroll
                for (int rg = 0; rg < 4; ++rg) {
                    const int row = mt * 16 + quad * 4 + rg;
                    Sp[(wave * 32 + row) * 40 + l16]      = s0[rg];
                    Sp[(wave * 32 + row) * 40 + 16 + l16] = s1[rg];
                }
            }
            __syncthreads();

            // ---- V prefetch (consumed in PV; latency covered by softmax) ----
            short8 vb[8];
#pragma unroll
            for (int nt = 0; nt < 8; ++nt)
                vb[nt] = *(const short8*)
                    &VT[(vrow + dchunk + nt * 16 + l16) * SEQ + j * 32 + quad * 8];

            // ---- reduce 8 partials + online softmax (16 threads per row) ----
            float sx = 0.f, sy = 0.f;
#pragma unroll
            for (int w = 0; w < 8; ++w) {
                const float2 pp = *(const float2*)&Sp[(w * 32 + rr) * 40 + c0];
                sx += pp.x; sy += pp.y;
            }
            float s0v = sx * 0.03125f, s1v = sy * 0.03125f;
            const int keyg = j * 32 + c0;
            const int rowg = q0 + rr;
            if (keyg + 0 > rowg) s0v = -INFINITY;
            if (keyg + 1 > rowg) s1v = -INFINITY;
            float mx = fmaxf(s0v, s1v);
#pragma unroll
            for (int off = 1; off < 16; off <<= 1) mx = fmaxf(mx, __shfl_xor(mx, off));
            const float mold = mS[rr];
            const float mnew = fmaxf(mold, mx);
            const float p0 = __expf(s0v - mnew), p1 = __expf(s1v - mnew);
            float rs = p0 + p1;
#pragma unroll
            for (int off = 1; off < 16; off <<= 1) rs += __shfl_xor(rs, off);
            const float alpha = __expf(mold - mnew);
            if ((tid & 15) == 0) {
                mS[rr] = mnew;
                lS[rr] = lS[rr] * alpha + rs;
                aS[rr] = alpha;
            }
            {
                union { __hip_bfloat162 h; u32 u; } pk;
                pk.h = __float22bfloat162_rn(float2{p0, p1});
                *(u32*)&Pl[rr * 40 + c0] = pk.u;
            }
            __syncthreads();

            // ---- rescale o by alpha ----
#pragma unroll
            for (int mt = 0; mt < 2; ++mt) {
                float a0 = aS[mt * 16 + quad * 4 + 0];
                float a1 = aS[mt * 16 + quad * 4 + 1];
                float a2 = aS[mt * 16 + quad * 4 + 2];
                float a3 = aS[mt * 16 + quad * 4 + 3];
#pragma unroll
                for (int nt = 0; nt < 8; ++nt) {
                    o[mt][nt][0] *= a0; o[mt][nt][1] *= a1;
                    o[mt][nt][2] *= a2; o[mt][nt][3] *= a3;
                }
            }
            // ---- PV: P (A-frag from LDS) x V-chunk ----
            short8 pa[2];
#pragma unroll
            for (int mt = 0; mt < 2; ++mt)
                pa[mt] = *(const short8*)&Pl[(mt * 16 + l16) * 40 + quad * 8];
#pragma unroll
            for (int nt = 0; nt < 8; ++nt)
#pragma unroll
                for (int mt = 0; mt < 2; ++mt)
                    o[mt][nt] = __builtin_amdgcn_mfma_f32_16x16x32_bf16(
                        pa[mt], vb[nt], o[mt][nt], 0, 0, 0);
            // next iter's Sp writes are pre-barrier-1; Pl/aS reads here are safe.
        }

        // ---- epilogue for this q-tile ----
#pragma unroll
        for (int mt = 0; mt < 2; ++mt) {
            float li0 = 1.f / lS[mt * 16 + quad * 4 + 0];
            float li1 = 1.f / lS[mt * 16 + quad * 4 + 1];
            float li2 = 1.f / lS[mt * 16 + quad * 4 + 2];
            float li3 = 1.f / lS[mt * 16 + quad * 4 + 3];
#pragma unroll
            for (int nt = 0; nt < 8; ++nt) {
                const size_t base = (qrow + q0 + mt * 16 + quad * 4) * DIM + wave * 128 + nt * 16 + l16;
                out[base]           = o[mt][nt][0] * li0;
                out[base + DIM]     = o[mt][nt][1] * li1;
                out[base + 2 * DIM] = o[mt][nt][2] * li2;
                out[base + 3 * DIM] = o[mt][nt][3] * li3;
            }
        }
        __syncthreads();   // epilogue lS reads done before next pass re-inits
    }
}

extern "C" void kernel_launch(void* const* d_in, const int* in_sizes, int n_in,
                              void* d_out, int out_size, void* d_ws, size_t ws_size,
                              hipStream_t stream) {
    const float* query = (const float*)d_in[0];
    const float* key   = (const float*)d_in[1];
    const float* value = (const float*)d_in[2];
    const float* ctx   = (const float*)d_in[3];
    const float* Wq    = (const float*)d_in[4];
    const float* bq    = (const float*)d_in[5];
    const float* Wk    = (const float*)d_in[6];
    const float* bk    = (const float*)d_in[7];
    const float* Wv    = (const float*)d_in[8];
    const float* bv    = (const float*)d_in[9];

    // workspace layout (bf16), with aliasing to stay small:
    //  A = xq  -> later overwritten with kw (projk output)
    //  B = xk
    //  C = xv  -> later overwritten with qw (projq output)
    //  D = vw  (vT)
    ushort_t* A = (ushort_t*)d_ws;
    ushort_t* B = A + (size_t)BSD;
    ushort_t* C = B + (size_t)BSD;
    ushort_t* D = C + (size_t)BSD;
    ushort_t* wqb = D + (size_t)BSD;
    ushort_t* wkb = wqb + (size_t)DD;
    ushort_t* wvb = wkb + (size_t)DD;
    float* out = (float*)d_out;

    {   // convert everything to bf16 (ctx folded into q/k)
        const long total = 3L * (BSD / 4) + 3L * (DD / 4);
        convert_kernel<<<dim3((unsigned)(total / 256)), dim3(256), 0, stream>>>(
            query, key, value, ctx, Wq, Wk, Wv, A, B, C, wqb, wkb, wvb);
    }

    const dim3 pg((BATCH * SEQ) / 128, DIM / 128);  // (128, 8)
    // order matters for aliasing: v first (reads C), then q (writes C), then k (writes A)
    gemm_bf16<<<pg, dim3(256), 0, stream>>>(C, wvb, bv, D, 1);  // vT
    gemm_bf16<<<pg, dim3(256), 0, stream>>>(A, wqb, bq, C, 0);  // q  (xv dead)
    gemm_bf16<<<pg, dim3(256), 0, stream>>>(B, wkb, bk, A, 0);  // k  (xq dead)

    // grid: 8 batches x 32 balanced pairs of 32-row q-tiles
    attn_kernel<<<dim3(BATCH * (SEQ / 64)), dim3(512), 0, stream>>>(C, A, D, out);
}